// Round 8
// baseline (113.924 us; speedup 1.0000x reference)
//
#include <hip/hip_runtime.h>
#include <hip/hip_bf16.h>
#include <stdint.h>

#define NROWS 4096
#define DIMS  2048
#define BM    128
#define BK    64
#define NTILES (DIMS / BK)   // 32
#define NTB   (NROWS / BM)   // 32 -> 1024 blocks
#define MARGIN_F 0.3f

typedef __attribute__((ext_vector_type(8))) short bf16x8;
typedef __attribute__((ext_vector_type(4))) float f32x4;
typedef __attribute__((ext_vector_type(4))) unsigned short us4;

__device__ inline unsigned short f2bf(float x) {
  union { float f; unsigned int u; } c; c.f = x;
  unsigned int lsb = (c.u >> 16) & 1u;
  c.u += 0x7fffu + lsb;               // round-to-nearest-even
  return (unsigned short)(c.u >> 16);
}

__device__ inline void atomicMaxF(float* addr, float v) {
  if (v >= 0.f) atomicMax((int*)addr, __float_as_int(v));
  else          atomicMin((unsigned int*)addr, __float_as_uint(v));
}
__device__ inline void atomicMinF(float* addr, float v) {
  if (v >= 0.f) atomicMin((int*)addr, __float_as_int(v));
  else          atomicMax((unsigned int*)addr, __float_as_uint(v));
}

__device__ inline void load_lds16(const void* g, void* l) {
  __builtin_amdgcn_global_load_lds(
      (const __attribute__((address_space(1))) void*)(g),
      (__attribute__((address_space(3))) void*)(l), 16, 0, 0);
}

// ---------------- normalize rows to bf16 + init dap/dan ----------------
__global__ __launch_bounds__(256) void norm_kernel(const float* __restrict__ in,
                                                   short* __restrict__ l2,
                                                   float* __restrict__ dap,
                                                   float* __restrict__ dan) {
  int row = blockIdx.x;
  int t = threadIdx.x;
  const float4* rin = (const float4*)(in + (size_t)row * DIMS);
  float4 v0 = rin[t];
  float4 v1 = rin[t + 256];
  float ss = v0.x*v0.x + v0.y*v0.y + v0.z*v0.z + v0.w*v0.w
           + v1.x*v1.x + v1.y*v1.y + v1.z*v1.z + v1.w*v1.w;
  #pragma unroll
  for (int s = 1; s < 64; s <<= 1) ss += __shfl_xor(ss, s);
  __shared__ float wsum[4];
  if ((t & 63) == 0) wsum[t >> 6] = ss;
  __syncthreads();
  float tot = wsum[0] + wsum[1] + wsum[2] + wsum[3];
  float rn = 1.0f / sqrtf(tot);
  short* orow = l2 + (size_t)row * DIMS;
  us4 o0, o1;
  o0.x = f2bf(v0.x * rn); o0.y = f2bf(v0.y * rn);
  o0.z = f2bf(v0.z * rn); o0.w = f2bf(v0.w * rn);
  o1.x = f2bf(v1.x * rn); o1.y = f2bf(v1.y * rn);
  o1.z = f2bf(v1.z * rn); o1.w = f2bf(v1.w * rn);
  *(us4*)(orow + 4 * t) = o0;
  *(us4*)(orow + 4 * t + 1024) = o1;
  if (t == 0) { dap[row] = -__builtin_inff(); dan[row] = __builtin_inff(); }
}

// ---------------- fused GEMM (G = L . L^T) + masked row max/min ----------------
// 128x128 tile, 4 waves (2x2, wave tile 64x64), BK=64, 64 KB LDS total ->
// 2 INDEPENDENT blocks/CU (cross-block MFMA/VMEM overlap hides phase overhead,
// m114 mechanism). 4 phases/K-tile (quadrant = m-half x ks), 8 MFMA each:
// {[P1/P3: vmcnt(4) gate + s_barrier]; ds_read frags; stage 1 granule;
//  lgkmcnt(0); setprio(1); 8 MFMA; setprio(0)}. Gates wait granules staged
// 4 phases earlier (per-thread vmcnt; barrier publishes cross-wave).
// LDS per set per op: [2 ks][128 rows][32 k] bf16 = 16 KB, chunk-swizzled
// q = c ^ ((row>>1)&3); staging linear dest + pre-swizzled coalesced source
// (verified r4-r7: 0 bank conflicts, correct).
__global__ __launch_bounds__(256) void gemm_reduce_kernel(
    const short* __restrict__ l2, const int* __restrict__ tgt,
    float* __restrict__ dap, float* __restrict__ dan) {
  __shared__ __attribute__((aligned(16))) short ldsA[2][8192];  // 2 sets x 16 KB
  __shared__ __attribute__((aligned(16))) short ldsB[2][8192];

  // XCD-chunked bijective swizzle (1024 blocks, 8 XCDs -> 128 contiguous per XCD)
  int c = blockIdx.x;
  int swz = (c & 7) * 128 + (c >> 3);
  int bi = swz >> 5, bj = swz & 31;

  int tid = threadIdx.x;
  int lane = tid & 63, w = tid >> 6;
  int wr = w >> 1;        // 0..1  (M half: 64 rows)
  int nc = w & 1;         // 0..1  (N half: 64 cols)

  f32x4 acc[4][4];
  #pragma unroll
  for (int m = 0; m < 4; m++)
    #pragma unroll
    for (int n = 0; n < 4; n++) acc[m][n] = (f32x4){0.f, 0.f, 0.f, 0.f};

  // --- staging source: granule = (op, ks) = [128 rows][32 k] = 8 KB,
  //     2 insts/thread (j=0: rows 0-63, j=1: rows 64-127) ---
  int srow = tid >> 2;                               // 0..63
  int qq = (tid & 3) ^ ((tid >> 3) & 3);             // pre-swizzled chunk
  const short* gA = l2 + ((size_t)(bi * BM + srow)) * DIMS + qq * 8;
  const short* gB = l2 + ((size_t)(bj * BM + srow)) * DIMS + qq * 8;

  // --- fragment read offsets (shorts, within a ks-granule) ---
  int laneq = lane & 15, g = lane >> 4;
  int fc = (g ^ ((laneq >> 1) & 3)) * 8;             // swizzled chunk slot
  int aOff = (wr * 64 + laneq) * 32 + fc;
  int bOff = (nc * 64 + laneq) * 32 + fc;

  bf16x8 aU[2], aV[2], bR[4];

  #define STAGE_A(T, KS, P)                                                   \
    do {                                                                      \
      load_lds16(gA + (size_t)(T) * 64 + (KS) * 32,                           \
                 &ldsA[P][(KS) * 4096 + w * 512]);                            \
      load_lds16(gA + (size_t)64 * DIMS + (size_t)(T) * 64 + (KS) * 32,       \
                 &ldsA[P][(KS) * 4096 + 2048 + w * 512]);                     \
    } while (0)
  #define STAGE_B(T, KS, P)                                                   \
    do {                                                                      \
      load_lds16(gB + (size_t)(T) * 64 + (KS) * 32,                           \
                 &ldsB[P][(KS) * 4096 + w * 512]);                            \
      load_lds16(gB + (size_t)64 * DIMS + (size_t)(T) * 64 + (KS) * 32,       \
                 &ldsB[P][(KS) * 4096 + 2048 + w * 512]);                     \
    } while (0)

  #define READ_A(DST, MB, KS, P)                                              \
    _Pragma("unroll")                                                         \
    for (int m = 0; m < 2; m++)                                               \
      DST[m] = *(const bf16x8*)&ldsA[P][(KS) * 4096 + aOff + ((MB) + m) * 512];
  #define READ_B(DST, KS, P)                                                  \
    _Pragma("unroll")                                                         \
    for (int n = 0; n < 4; n++)                                               \
      DST[n] = *(const bf16x8*)&ldsB[P][(KS) * 4096 + bOff + n * 512];

  #define MFMA8(MB, AR, BR)                                                   \
    __builtin_amdgcn_s_setprio(1);                                            \
    _Pragma("unroll")                                                         \
    for (int m = 0; m < 2; m++)                                               \
      _Pragma("unroll")                                                       \
      for (int n = 0; n < 4; n++)                                             \
        acc[(MB) + m][n] = __builtin_amdgcn_mfma_f32_16x16x32_bf16(           \
            AR[m], BR[n], acc[(MB) + m][n], 0, 0, 0);                         \
    __builtin_amdgcn_s_setprio(0);

  #define SB __builtin_amdgcn_sched_barrier(0);
  #define LGKM0                                                               \
    asm volatile("s_waitcnt lgkmcnt(0)" ::: "memory");                        \
    SB
  #define GATE4                                                               \
    asm volatile("s_waitcnt vmcnt(4)" ::: "memory");                          \
    SB                                                                        \
    __builtin_amdgcn_s_barrier();                                             \
    SB

  // ITER: compute current tile from set P (4 phases), stage tile TN into P^1.
  // Granule order staged: P1:A0 P2:B0 P3:A1 P4:B1 (2 insts each, 8/tile).
  // Gate P1: waits this tile's A0,B0 (issued 4 phases ago). Gate P3: A1,B1.
  #define ITER(P, TN)                                                         \
    do {                                                                      \
      /* P1: (m0-1, ks0) */                                                   \
      GATE4                                                                   \
      READ_A(aU, 0, 0, P)                                                     \
      READ_B(bR, 0, P)                                                        \
      STAGE_A(TN, 0, (P) ^ 1);                                                \
      LGKM0                                                                   \
      MFMA8(0, aU, bR)                                                        \
      /* P2: (m2-3, ks0) */                                                   \
      READ_A(aV, 2, 0, P)                                                     \
      STAGE_B(TN, 0, (P) ^ 1);                                                \
      LGKM0                                                                   \
      MFMA8(2, aV, bR)                                                        \
      /* P3: (m0-1, ks1) */                                                   \
      GATE4                                                                   \
      READ_A(aU, 0, 1, P)                                                     \
      READ_B(bR, 1, P)                                                        \
      STAGE_A(TN, 1, (P) ^ 1);                                                \
      LGKM0                                                                   \
      MFMA8(0, aU, bR)                                                        \
      /* P4: (m2-3, ks1) */                                                   \
      READ_A(aV, 2, 1, P)                                                     \
      STAGE_B(TN, 1, (P) ^ 1);                                                \
      LGKM0                                                                   \
      MFMA8(2, aV, bR)                                                        \
    } while (0)

  // prologue: stage tile0's 4 granules into set0 (oldest-first = gate order)
  STAGE_A(0, 0, 0);
  STAGE_B(0, 0, 0);
  STAGE_A(0, 1, 0);
  STAGE_B(0, 1, 0);

  #pragma unroll 1
  for (int kt = 0; kt < NTILES; kt += 2) {
    ITER(0, kt + 1);                                   // kt+1 <= 31
    ITER(1, (kt + 2 < NTILES) ? kt + 2 : NTILES - 1);  // last: benign re-stage
  }

  // ---- fused masked reduction ----
  // acc[m][n][r] = G[bi*128 + wr*64 + m*16 + (lane>>4)*4 + r]
  //                 [bj*128 + nc*64 + n*16 + (lane&15)]
  int tcol[4];
  #pragma unroll
  for (int n = 0; n < 4; n++) tcol[n] = tgt[bj * BM + nc * 64 + n * 16 + (lane & 15)];
  int rbase = bi * BM + wr * 64 + (lane >> 4) * 4;

  #pragma unroll
  for (int m = 0; m < 4; m++) {
    #pragma unroll
    for (int r = 0; r < 4; r++) {
      int grow = rbase + m * 16 + r;
      int trow = tgt[grow];
      float ap = -__builtin_inff(), an = __builtin_inff();
      #pragma unroll
      for (int n = 0; n < 4; n++) {
        float d = -acc[m][n][r];
        bool same = (trow == tcol[n]);
        ap = same ? fmaxf(ap, d) : ap;
        an = same ? an : fminf(an, d);
      }
      #pragma unroll
      for (int s = 1; s < 16; s <<= 1) {
        ap = fmaxf(ap, __shfl_xor(ap, s));
        an = fminf(an, __shfl_xor(an, s));
      }
      if ((lane & 15) == 0) {
        atomicMaxF(&dap[grow], ap);
        atomicMinF(&dan[grow], an);
      }
    }
  }
  #undef STAGE_A
  #undef STAGE_B
  #undef READ_A
  #undef READ_B
  #undef MFMA8
  #undef SB
  #undef LGKM0
  #undef GATE4
  #undef ITER
}

// ---------------- final loss ----------------
__global__ __launch_bounds__(256) void loss_kernel(const float* __restrict__ dap,
                                                   const float* __restrict__ dan,
                                                   float* __restrict__ out) {
  int t = threadIdx.x;
  float s = 0.f;
  for (int i = t; i < NROWS; i += 256) {
    float v = dap[i] - dan[i] + MARGIN_F;
    s += v > 0.f ? v : 0.f;
  }
  #pragma unroll
  for (int sh = 1; sh < 64; sh <<= 1) s += __shfl_xor(s, sh);
  __shared__ float ws[4];
  if ((t & 63) == 0) ws[t >> 6] = s;
  __syncthreads();
  if (t == 0) out[0] = (ws[0] + ws[1] + ws[2] + ws[3]) * (1.0f / (float)NROWS);
}

extern "C" void kernel_launch(void* const* d_in, const int* in_sizes, int n_in,
                              void* d_out, int out_size, void* d_ws, size_t ws_size,
                              hipStream_t stream) {
  const float* inputs = (const float*)d_in[0];
  const int* targets = (const int*)d_in[1];
  short* l2 = (short*)d_ws;
  float* dap = (float*)((char*)d_ws + (size_t)NROWS * DIMS * 2);
  float* dan = dap + NROWS;
  float* out = (float*)d_out;

  hipLaunchKernelGGL(norm_kernel, dim3(NROWS), dim3(256), 0, stream,
                     inputs, l2, dap, dan);
  hipLaunchKernelGGL(gemm_reduce_kernel, dim3(NTB * NTB), dim3(256), 0, stream,
                     l2, targets, dap, dan);
  hipLaunchKernelGGL(loss_kernel, dim3(1), dim3(256), 0, stream, dap, dan, out);
}

// Round 9
// 72.421 us; speedup vs baseline: 1.5731x; 1.5731x over previous
//
#include <hip/hip_runtime.h>
#include <hip/hip_bf16.h>
#include <stdint.h>

#define NROWS 4096
#define DIMS  2048
#define BM    256
#define BK    64              // 64 int8 per K-tile = 64 B rows
#define NTILES (DIMS / BK)    // 32
#define NTB   (NROWS / BM)    // 16 -> 256 blocks
#define MARGIN_F 0.3f

typedef __attribute__((ext_vector_type(4))) int   i32x4;
typedef __attribute__((ext_vector_type(4))) float f32x4;

__device__ inline void atomicMaxF(float* addr, float v) {
  if (v >= 0.f) atomicMax((int*)addr, __float_as_int(v));
  else          atomicMin((unsigned int*)addr, __float_as_uint(v));
}
__device__ inline void atomicMinF(float* addr, float v) {
  if (v >= 0.f) atomicMin((int*)addr, __float_as_int(v));
  else          atomicMax((unsigned int*)addr, __float_as_uint(v));
}

__device__ inline void load_lds16(const void* g, void* l) {
  __builtin_amdgcn_global_load_lds(
      (const __attribute__((address_space(1))) void*)(g),
      (__attribute__((address_space(3))) void*)(l), 16, 0, 0);
}

// ------- normalize + per-row int8 quantization (q = rint(x*127/amax)) -------
__global__ __launch_bounds__(256) void norm_kernel(const float* __restrict__ in,
                                                   char* __restrict__ l2q,
                                                   float* __restrict__ recip,
                                                   float* __restrict__ dap,
                                                   float* __restrict__ dan) {
  int row = blockIdx.x;
  int t = threadIdx.x;
  const float4* rin = (const float4*)(in + (size_t)row * DIMS);
  float4 v0 = rin[t];
  float4 v1 = rin[t + 256];
  float ss = v0.x*v0.x + v0.y*v0.y + v0.z*v0.z + v0.w*v0.w
           + v1.x*v1.x + v1.y*v1.y + v1.z*v1.z + v1.w*v1.w;
  float am = fmaxf(fmaxf(fmaxf(fabsf(v0.x), fabsf(v0.y)), fmaxf(fabsf(v0.z), fabsf(v0.w))),
                   fmaxf(fmaxf(fabsf(v1.x), fabsf(v1.y)), fmaxf(fabsf(v1.z), fabsf(v1.w))));
  #pragma unroll
  for (int s = 1; s < 64; s <<= 1) {
    ss += __shfl_xor(ss, s);
    am = fmaxf(am, __shfl_xor(am, s));
  }
  __shared__ float wsum[4], wmax[4];
  if ((t & 63) == 0) { wsum[t >> 6] = ss; wmax[t >> 6] = am; }
  __syncthreads();
  float tot = wsum[0] + wsum[1] + wsum[2] + wsum[3];
  float amax = fmaxf(fmaxf(wmax[0], wmax[1]), fmaxf(wmax[2], wmax[3]));
  float rn = 1.0f / sqrtf(tot);
  float qs = 127.0f / amax;
  int q0 = (int)rintf(v0.x * qs), q1 = (int)rintf(v0.y * qs);
  int q2 = (int)rintf(v0.z * qs), q3 = (int)rintf(v0.w * qs);
  int q4 = (int)rintf(v1.x * qs), q5 = (int)rintf(v1.y * qs);
  int q6 = (int)rintf(v1.z * qs), q7 = (int)rintf(v1.w * qs);
  int p0 = (q0 & 255) | ((q1 & 255) << 8) | ((q2 & 255) << 16) | (q3 << 24);
  int p1 = (q4 & 255) | ((q5 & 255) << 8) | ((q6 & 255) << 16) | (q7 << 24);
  int* orow = (int*)(l2q + (size_t)row * DIMS);
  orow[t] = p0;
  orow[t + 256] = p1;
  if (t == 0) {
    recip[row] = amax * rn / 127.0f;
    dap[row] = -__builtin_inff();
    dan[row] = __builtin_inff();
  }
}

// ---------------- fused int8 GEMM (acc = Q . Q^T) + masked row max/min ----------------
// 256x256 tile, 8 waves (2M x 4N, wave tile 128x64), BK=64 int8,
// mfma_i32_16x16x64_i8 (one MFMA covers full K-tile: 32 MFMA/wave/tile).
// LDS: 3 sets x (A 16KB + B 16KB) = 96 KB; stage tile t+2 while computing t
// -> 6 loads in flight across the vmcnt(6) gate (T4, never a cold drain).
// Tile layout [256 rows][64 B], chunk-swizzled q = c ^ ((row>>1)&3) --
// byte-identical geometry to r4-r7's verified zero-conflict bf16 granule;
// staging linear LDS dest + pre-swizzled coalesced global source.
// 2 phases/tile: {stage granule; [P1: vmcnt(6)] barrier; ds_read frags;
// lgkmcnt(0); setprio(1); 16 MFMA; setprio(0)}.
__global__ __launch_bounds__(512, 2) void gemm_reduce_kernel(
    const char* __restrict__ l2q, const int* __restrict__ tgt,
    const float* __restrict__ recip,
    float* __restrict__ dap, float* __restrict__ dan) {
  __shared__ __attribute__((aligned(16))) char ldsbuf[98304];  // 3 x (16K A + 16K B)

  // XCD-chunked bijective swizzle (256 blocks, 8 XCDs -> 32 contiguous per XCD)
  int c = blockIdx.x;
  int swz = (c & 7) * 32 + (c >> 3);
  int bi = swz >> 4, bj = swz & 15;

  int tid = threadIdx.x;
  int lane = tid & 63, w = tid >> 6;
  int wr = w >> 2;        // 0..1  (M half: 128 rows)
  int nc = w & 3;         // 0..3  (N quarter: 64 cols)

  i32x4 acc[8][4];
  #pragma unroll
  for (int m = 0; m < 8; m++)
    #pragma unroll
    for (int n = 0; n < 4; n++) acc[m][n] = (i32x4){0, 0, 0, 0};

  // --- staging source: row = tid>>2 (j=0) / +128 (j=1); data chunk
  //     q = (tid&3) ^ ((row>>1)&3); 4 consecutive threads = 64 B contiguous ---
  int srow = tid >> 2;                               // 0..127
  int qq = (tid & 3) ^ ((tid >> 3) & 3);
  const char* gA = l2q + ((size_t)(bi * BM + srow)) * DIMS + qq * 16;
  const char* gB = l2q + ((size_t)(bj * BM + srow)) * DIMS + qq * 16;

  // --- fragment read offsets (bytes): same verified swizzle ---
  int laneq = lane & 15, g = lane >> 4;
  int fcB = (g ^ ((laneq >> 1) & 3)) * 16;           // swizzled 16B chunk slot
  int aOffB = (wr * 128 + laneq) * 64 + fcB;
  int bOffB = 16384 + (nc * 64 + laneq) * 64 + fcB;

  i32x4 aU[4], aV[4], bR[4];

  #define STAGE_A(T, DOFF)                                                    \
    do {                                                                      \
      load_lds16(gA + (size_t)(T) * 64, &ldsbuf[(DOFF) + w * 1024]);          \
      load_lds16(gA + (size_t)128 * DIMS + (size_t)(T) * 64,                  \
                 &ldsbuf[(DOFF) + 8192 + w * 1024]);                          \
    } while (0)
  #define STAGE_B(T, DOFF)                                                    \
    do {                                                                      \
      load_lds16(gB + (size_t)(T) * 64, &ldsbuf[(DOFF) + 16384 + w * 1024]);  \
      load_lds16(gB + (size_t)128 * DIMS + (size_t)(T) * 64,                  \
                 &ldsbuf[(DOFF) + 24576 + w * 1024]);                         \
    } while (0)

  #define READ_A4(DST, MB, COFF)                                              \
    _Pragma("unroll")                                                         \
    for (int m = 0; m < 4; m++)                                               \
      DST[m] = *(const i32x4*)&ldsbuf[(COFF) + aOffB + ((MB) + m) * 1024];
  #define READ_B4(DST, COFF)                                                  \
    _Pragma("unroll")                                                         \
    for (int n = 0; n < 4; n++)                                               \
      DST[n] = *(const i32x4*)&ldsbuf[(COFF) + bOffB + n * 1024];

  #define MFMA16(MB, AR, BR)                                                  \
    __builtin_amdgcn_s_setprio(1);                                            \
    _Pragma("unroll")                                                         \
    for (int m = 0; m < 4; m++)                                               \
      _Pragma("unroll")                                                       \
      for (int n = 0; n < 4; n++)                                             \
        acc[(MB) + m][n] = __builtin_amdgcn_mfma_i32_16x16x64_i8(             \
            AR[m], BR[n], acc[(MB) + m][n], 0, 0, 0);                         \
    __builtin_amdgcn_s_setprio(0);

  #define SB __builtin_amdgcn_sched_barrier(0);
  #define LGKM0                                                               \
    asm volatile("s_waitcnt lgkmcnt(0)" ::: "memory");                        \
    SB
  #define VM6                                                                 \
    asm volatile("s_waitcnt vmcnt(6)" ::: "memory");                          \
    SB
  #define BAR __builtin_amdgcn_s_barrier(); SB

  // prologue: tiles 0,1 into sets 0,1 (A,B pair order = gate drain order)
  STAGE_A(0, 0);
  STAGE_B(0, 0);
  STAGE_A(1, 32768);
  STAGE_B(1, 32768);

  int curOff = 0, dstOff = 65536;
  #pragma unroll 1
  for (int kt = 0; kt < NTILES; ++kt) {
    int tn = (kt + 2 < NTILES) ? kt + 2 : NTILES - 1;  // tail: benign re-stage
    /* P1: (m0-3) */
    STAGE_A(tn, dstOff);
    VM6
    BAR
    READ_B4(bR, curOff)
    READ_A4(aU, 0, curOff)
    LGKM0
    MFMA16(0, aU, bR)
    /* P2: (m4-7), B reused in regs */
    STAGE_B(tn, dstOff);
    BAR
    READ_A4(aV, 4, curOff)
    LGKM0
    MFMA16(4, aV, bR)
    curOff = (curOff == 65536) ? 0 : curOff + 32768;
    dstOff = (dstOff == 65536) ? 0 : dstOff + 32768;
  }

  // ---- fused masked reduction (C/D layout shape-determined, same as bf16) ----
  // acc[m][n][r] = Gq[bi*256 + wr*128 + m*16 + (lane>>4)*4 + r]
  //                  [bj*256 + nc*64  + n*16 + (lane&15)]
  int tcol[4];
  float tcr[4];
  #pragma unroll
  for (int n = 0; n < 4; n++) {
    int idx = bj * BM + nc * 64 + n * 16 + laneq;
    tcol[n] = tgt[idx];
    tcr[n] = recip[idx];
  }
  int rbase = bi * BM + wr * 128 + g * 4;

  #pragma unroll
  for (int m = 0; m < 8; m++) {
    #pragma unroll
    for (int r = 0; r < 4; r++) {
      int grow = rbase + m * 16 + r;
      int trow = tgt[grow];
      float rrw = recip[grow];
      float ap = -__builtin_inff(), an = __builtin_inff();
      #pragma unroll
      for (int n = 0; n < 4; n++) {
        float d = -(float)acc[m][n][r] * rrw * tcr[n];
        bool same = (trow == tcol[n]);
        ap = same ? fmaxf(ap, d) : ap;
        an = same ? an : fminf(an, d);
      }
      #pragma unroll
      for (int s = 1; s < 16; s <<= 1) {
        ap = fmaxf(ap, __shfl_xor(ap, s));
        an = fminf(an, __shfl_xor(an, s));
      }
      if (laneq == 0) {
        atomicMaxF(&dap[grow], ap);
        atomicMinF(&dan[grow], an);
      }
    }
  }
  #undef STAGE_A
  #undef STAGE_B
  #undef READ_A4
  #undef READ_B4
  #undef MFMA16
  #undef SB
  #undef LGKM0
  #undef VM6
  #undef BAR
}

// ---------------- final loss ----------------
__global__ __launch_bounds__(256) void loss_kernel(const float* __restrict__ dap,
                                                   const float* __restrict__ dan,
                                                   float* __restrict__ out) {
  int t = threadIdx.x;
  float s = 0.f;
  for (int i = t; i < NROWS; i += 256) {
    float v = dap[i] - dan[i] + MARGIN_F;
    s += v > 0.f ? v : 0.f;
  }
  #pragma unroll
  for (int sh = 1; sh < 64; sh <<= 1) s += __shfl_xor(s, sh);
  __shared__ float ws[4];
  if ((t & 63) == 0) ws[t >> 6] = s;
  __syncthreads();
  if (t == 0) out[0] = (ws[0] + ws[1] + ws[2] + ws[3]) * (1.0f / (float)NROWS);
}

extern "C" void kernel_launch(void* const* d_in, const int* in_sizes, int n_in,
                              void* d_out, int out_size, void* d_ws, size_t ws_size,
                              hipStream_t stream) {
  const float* inputs = (const float*)d_in[0];
  const int* targets = (const int*)d_in[1];
  char* l2q = (char*)d_ws;
  float* recip = (float*)((char*)d_ws + (size_t)NROWS * DIMS);
  float* dap = recip + NROWS;
  float* dan = dap + NROWS;
  float* out = (float*)d_out;

  hipLaunchKernelGGL(norm_kernel, dim3(NROWS), dim3(256), 0, stream,
                     inputs, l2q, recip, dap, dan);
  hipLaunchKernelGGL(gemm_reduce_kernel, dim3(NTB * NTB), dim3(512), 0, stream,
                     l2q, targets, recip, dap, dan);
  hipLaunchKernelGGL(loss_kernel, dim3(1), dim3(256), 0, stream, dap, dan, out);
}